// Round 1
// baseline (285.456 us; speedup 1.0000x reference)
//
#include <hip/hip_runtime.h>

// ConstraintLoss: out = mean((pred-targ)^2) + mean_b( ||sum_k (x_k - dyn(x_{k-1}, u_k))|| + sum_{o,k}(dist - rad2) )
// N_INTERVALS=40, DT=0.25, CAR_WIDTH=2.0, N_OBST=3
// predictions/targets: (B,240) f32; inputs: (B,13) f32; out: scalar f32.

#define NTHREADS 256

__global__ void zero_ws_kernel(float* ws) {
    ws[0] = 0.0f;
    ws[1] = 0.0f;
}

__global__ __launch_bounds__(NTHREADS) void constraint_main_kernel(
    const float* __restrict__ pred,
    const float* __restrict__ targ,
    const float* __restrict__ inp,
    float* __restrict__ ws,
    int B)
{
    const float DT = 0.25f;
    int row = blockIdx.x * NTHREADS + threadIdx.x;

    float mse = 0.0f;
    float cons = 0.0f;

    if (row < B) {
        const float4* p4 = reinterpret_cast<const float4*>(pred + (size_t)row * 240);
        const float4* t4 = reinterpret_cast<const float4*>(targ + (size_t)row * 240);
        const float*  in = inp + (size_t)row * 13;

        // initial state + obstacles
        float x0px = in[0], x0py = in[1], x0th = in[2], x0v = in[3];
        float ox0 = in[4],  oy0 = in[5];
        float ox1 = in[7],  oy1 = in[8];
        float ox2 = in[10], oy2 = in[11];
        float r0_ = in[6]  + 2.0f;
        float r1_ = in[9]  + 2.0f;
        float r2_ = in[12] + 2.0f;
        float rad2sum = r0_ * r0_ + r1_ * r1_ + r2_ * r2_;

        float cv = 0.0f, sv = 0.0f;      // sum prev.v*cos(prev.th), prev.v*sin(prev.th)
        float sum_dist = 0.0f;
        float prev_th = x0th, prev_v = x0v;
        float4 xl = make_float4(0.f, 0.f, 0.f, 0.f);  // will hold x[39]

        // x pass: float4 j = x[k] = (px, py, th, v)
        #pragma unroll 4
        for (int k = 0; k < 40; ++k) {
            float4 pv = p4[k];
            float4 tv = t4[k];
            float d0 = pv.x - tv.x, d1 = pv.y - tv.y;
            float d2 = pv.z - tv.z, d3 = pv.w - tv.w;
            mse += d0 * d0 + d1 * d1 + d2 * d2 + d3 * d3;

            // dynamics contribution from prev (= x0 for k=0, else x[k-1])
            float s, c;
            __sincosf(prev_th, &s, &c);
            cv += prev_v * c;
            sv += prev_v * s;

            // obstacle distances at x[k]
            float dx, dy;
            dx = pv.x - ox0; dy = pv.y - oy0; sum_dist += sqrtf(dx * dx + dy * dy);
            dx = pv.x - ox1; dy = pv.y - oy1; sum_dist += sqrtf(dx * dx + dy * dy);
            dx = pv.x - ox2; dy = pv.y - oy2; sum_dist += sqrtf(dx * dx + dy * dy);

            prev_th = pv.z;
            prev_v  = pv.w;
            xl = pv;
        }

        // u pass: float4 (40+m) = (a_{2m}, w_{2m}, a_{2m+1}, w_{2m+1})
        float sum_a = 0.0f, sum_w = 0.0f;
        #pragma unroll 4
        for (int m = 0; m < 20; ++m) {
            float4 pv = p4[40 + m];
            float4 tv = t4[40 + m];
            float d0 = pv.x - tv.x, d1 = pv.y - tv.y;
            float d2 = pv.z - tv.z, d3 = pv.w - tv.w;
            mse += d0 * d0 + d1 * d1 + d2 * d2 + d3 * d3;
            sum_a += pv.x + pv.z;
            sum_w += pv.y + pv.w;
        }

        // telescoped dynamics residual
        float rr0 = xl.x - x0px - DT * cv;
        float rr1 = xl.y - x0py - DT * sv;
        float rr2 = xl.z - x0th - DT * sum_w;
        float rr3 = xl.w - x0v  - DT * sum_a;
        float dyn_err = sqrtf(rr0 * rr0 + rr1 * rr1 + rr2 * rr2 + rr3 * rr3);
        float obst_err = sum_dist - 40.0f * rad2sum;
        cons = dyn_err + obst_err;
    }

    // wave (64-lane) shuffle reduction
    #pragma unroll
    for (int off = 32; off > 0; off >>= 1) {
        mse  += __shfl_down(mse,  off);
        cons += __shfl_down(cons, off);
    }

    __shared__ float smse[NTHREADS / 64];
    __shared__ float scons[NTHREADS / 64];
    int wid  = threadIdx.x >> 6;
    int lane = threadIdx.x & 63;
    if (lane == 0) { smse[wid] = mse; scons[wid] = cons; }
    __syncthreads();
    if (threadIdx.x == 0) {
        float m = smse[0] + smse[1] + smse[2] + smse[3];
        float c = scons[0] + scons[1] + scons[2] + scons[3];
        atomicAdd(&ws[0], m);
        atomicAdd(&ws[1], c);
    }
}

__global__ void finalize_kernel(const float* __restrict__ ws, float* __restrict__ out, int B) {
    float nb = (float)B;
    out[0] = ws[0] / (nb * 240.0f) + ws[1] / nb;
}

extern "C" void kernel_launch(void* const* d_in, const int* in_sizes, int n_in,
                              void* d_out, int out_size, void* d_ws, size_t ws_size,
                              hipStream_t stream) {
    const float* pred = (const float*)d_in[0];
    const float* targ = (const float*)d_in[1];
    const float* inp  = (const float*)d_in[2];
    float* out = (float*)d_out;
    float* ws  = (float*)d_ws;

    int B = in_sizes[0] / 240;

    zero_ws_kernel<<<1, 1, 0, stream>>>(ws);
    int grid = (B + NTHREADS - 1) / NTHREADS;
    constraint_main_kernel<<<grid, NTHREADS, 0, stream>>>(pred, targ, inp, ws, B);
    finalize_kernel<<<1, 1, 0, stream>>>(ws, out, B);
}

// Round 2
// 270.216 us; speedup vs baseline: 1.0564x; 1.0564x over previous
//
#include <hip/hip_runtime.h>

// ConstraintLoss fused reduction.
// predictions/targets: (B,240) f32; inputs: (B,13) f32; out: scalar f32.
// Row split across 4 threads (sub = tid&3), interleaved float4 chunks for
// coalescing; telescoped dynamics => pure elementwise sums, no seq dep.

#define NTHREADS 256
#define ROWS_PER_BLOCK 64   // NTHREADS / 4

__global__ __launch_bounds__(NTHREADS) void constraint_main_kernel(
    const float* __restrict__ pred,
    const float* __restrict__ targ,
    const float* __restrict__ inp,
    float* __restrict__ partial,   // 2 floats per block, overwritten
    int B)
{
    const float DT = 0.25f;
    const int tid  = threadIdx.x;
    const int sub  = tid & 3;
    const int rloc = tid >> 2;
    const int row  = blockIdx.x * ROWS_PER_BLOCK + rloc;

    // Stage this block's inputs (64 rows x 13 f32) coalesced through LDS.
    __shared__ float sinp[ROWS_PER_BLOCK * 13];
    {
        const int base = blockIdx.x * ROWS_PER_BLOCK * 13;
        const int tot  = ROWS_PER_BLOCK * 13;
        const int avail = B * 13 - base;   // elements actually in bounds
        for (int idx = tid; idx < tot; idx += NTHREADS) {
            float v = 0.0f;
            if (idx < avail) v = inp[base + idx];
            sinp[idx] = v;
        }
    }
    __syncthreads();

    float mse = 0.0f, cons = 0.0f;

    if (row < B) {
        const float4* p4 = reinterpret_cast<const float4*>(pred + (size_t)row * 240);
        const float4* t4 = reinterpret_cast<const float4*>(targ + (size_t)row * 240);
        const float*  in = &sinp[rloc * 13];

        const float ox0 = in[4],  oy0 = in[5];
        const float ox1 = in[7],  oy1 = in[8];
        const float ox2 = in[10], oy2 = in[11];

        float cv = 0.0f, sv = 0.0f, sum_dist = 0.0f;
        float sum_a = 0.0f, sum_w = 0.0f;
        float xlx = 0.0f, xly = 0.0f, xlth = 0.0f, xlv = 0.0f;  // x[39], held by sub 3

        // States x[k], k = sub + 4*i, i = 0..9 (float4 = px,py,th,v)
        #pragma unroll
        for (int i = 0; i < 10; ++i) {
            const int k = sub + 4 * i;
            float4 pv = p4[k];
            float4 tv = t4[k];
            float d0 = pv.x - tv.x, d1 = pv.y - tv.y;
            float d2 = pv.z - tv.z, d3 = pv.w - tv.w;
            mse += d0 * d0 + d1 * d1 + d2 * d2 + d3 * d3;

            if (k != 39) {               // states 0..38 feed the telescoped sums
                float s, c;
                __sincosf(pv.z, &s, &c);
                cv += pv.w * c;
                sv += pv.w * s;
            } else {                     // state 39 = last state
                xlx = pv.x; xly = pv.y; xlth = pv.z; xlv = pv.w;
            }

            float dx, dy;
            dx = pv.x - ox0; dy = pv.y - oy0; sum_dist += sqrtf(dx * dx + dy * dy);
            dx = pv.x - ox1; dy = pv.y - oy1; sum_dist += sqrtf(dx * dx + dy * dy);
            dx = pv.x - ox2; dy = pv.y - oy2; sum_dist += sqrtf(dx * dx + dy * dy);
        }

        // Controls u: float4 idx 40..59 = (a,w,a,w); idx = 40 + sub + 4*i
        #pragma unroll
        for (int i = 0; i < 5; ++i) {
            const int m = 40 + sub + 4 * i;
            float4 pv = p4[m];
            float4 tv = t4[m];
            float d0 = pv.x - tv.x, d1 = pv.y - tv.y;
            float d2 = pv.z - tv.z, d3 = pv.w - tv.w;
            mse += d0 * d0 + d1 * d1 + d2 * d2 + d3 * d3;
            sum_a += pv.x + pv.z;
            sum_w += pv.y + pv.w;
        }

        // Combine partials across the 4 lanes of this row's group.
        #pragma unroll
        for (int m = 1; m < 4; m <<= 1) {
            cv       += __shfl_xor(cv, m);
            sv       += __shfl_xor(sv, m);
            sum_a    += __shfl_xor(sum_a, m);
            sum_w    += __shfl_xor(sum_w, m);
            sum_dist += __shfl_xor(sum_dist, m);
        }

        // Bring x[39] (in sub 3) to everyone in the group.
        const int lane = tid & 63;
        const int src  = lane | 3;
        xlx  = __shfl(xlx,  src);
        xly  = __shfl(xly,  src);
        xlth = __shfl(xlth, src);
        xlv  = __shfl(xlv,  src);

        if (sub == 0) {
            const float x0px = in[0], x0py = in[1], x0th = in[2], x0v = in[3];
            const float r0 = in[6]  + 2.0f;
            const float r1 = in[9]  + 2.0f;
            const float r2 = in[12] + 2.0f;
            float s, c;
            __sincosf(x0th, &s, &c);
            cv += x0v * c;       // prev for k=0 is x0
            sv += x0v * s;

            float rr0 = xlx  - x0px - DT * cv;
            float rr1 = xly  - x0py - DT * sv;
            float rr2 = xlth - x0th - DT * sum_w;
            float rr3 = xlv  - x0v  - DT * sum_a;
            float dyn_err = sqrtf(rr0 * rr0 + rr1 * rr1 + rr2 * rr2 + rr3 * rr3);
            float rad2sum = r0 * r0 + r1 * r1 + r2 * r2;
            cons = dyn_err + sum_dist - 40.0f * rad2sum;
        }
    }

    // Wave-level reduction (64 lanes), then cross-wave via LDS.
    #pragma unroll
    for (int off = 32; off > 0; off >>= 1) {
        mse  += __shfl_down(mse,  off);
        cons += __shfl_down(cons, off);
    }

    __shared__ float smse[NTHREADS / 64];
    __shared__ float scons[NTHREADS / 64];
    const int wid  = threadIdx.x >> 6;
    const int lane = threadIdx.x & 63;
    if (lane == 0) { smse[wid] = mse; scons[wid] = cons; }
    __syncthreads();
    if (threadIdx.x == 0) {
        float m = smse[0] + smse[1] + smse[2] + smse[3];
        float c = scons[0] + scons[1] + scons[2] + scons[3];
        partial[2 * blockIdx.x]     = m;   // overwrite: no zeroing pass needed
        partial[2 * blockIdx.x + 1] = c;
    }
}

__global__ __launch_bounds__(256) void finalize_kernel(
    const float* __restrict__ partial, float* __restrict__ out,
    int nblocks, int B)
{
    float m = 0.0f, c = 0.0f;
    for (int i = threadIdx.x; i < nblocks; i += 256) {
        m += partial[2 * i];
        c += partial[2 * i + 1];
    }
    #pragma unroll
    for (int off = 32; off > 0; off >>= 1) {
        m += __shfl_down(m, off);
        c += __shfl_down(c, off);
    }
    __shared__ float sm[4], sc[4];
    const int wid  = threadIdx.x >> 6;
    const int lane = threadIdx.x & 63;
    if (lane == 0) { sm[wid] = m; sc[wid] = c; }
    __syncthreads();
    if (threadIdx.x == 0) {
        float mm = sm[0] + sm[1] + sm[2] + sm[3];
        float cc = sc[0] + sc[1] + sc[2] + sc[3];
        float nb = (float)B;
        out[0] = mm / (nb * 240.0f) + cc / nb;
    }
}

extern "C" void kernel_launch(void* const* d_in, const int* in_sizes, int n_in,
                              void* d_out, int out_size, void* d_ws, size_t ws_size,
                              hipStream_t stream) {
    const float* pred = (const float*)d_in[0];
    const float* targ = (const float*)d_in[1];
    const float* inp  = (const float*)d_in[2];
    float* out = (float*)d_out;
    float* ws  = (float*)d_ws;

    const int B = in_sizes[0] / 240;
    const int grid = (B + ROWS_PER_BLOCK - 1) / ROWS_PER_BLOCK;

    constraint_main_kernel<<<grid, NTHREADS, 0, stream>>>(pred, targ, inp, ws, B);
    finalize_kernel<<<1, 256, 0, stream>>>(ws, out, grid, B);
}

// Round 4
// 268.505 us; speedup vs baseline: 1.0631x; 1.0064x over previous
//
#include <hip/hip_runtime.h>

// ConstraintLoss fused reduction, deep load-batch version.
// predictions/targets: (B,240) f32; inputs: (B,13) f32; out: scalar f32.
// Row split across 4 threads (sub = tid&3); each thread preloads its entire
// 480B share (15+15 float4) into registers before computing, so ~30 KB/wave
// of loads are in flight (latency-hiding via ILP, not occupancy).

#define NTHREADS 256
#define ROWS_PER_BLOCK 64   // NTHREADS / 4

__global__ __launch_bounds__(NTHREADS, 1) void constraint_main_kernel(
    const float* __restrict__ pred,
    const float* __restrict__ targ,
    const float* __restrict__ inp,
    float* __restrict__ partial,   // 2 floats per block, overwritten
    int B)
{
    const float DT = 0.25f;
    const int tid  = threadIdx.x;
    const int sub  = tid & 3;
    const int rloc = tid >> 2;
    const int row  = blockIdx.x * ROWS_PER_BLOCK + rloc;

    // Stage this block's inputs (64 rows x 13 f32) coalesced through LDS.
    __shared__ float sinp[ROWS_PER_BLOCK * 13];
    {
        const int base = blockIdx.x * ROWS_PER_BLOCK * 13;
        const int tot  = ROWS_PER_BLOCK * 13;
        const int avail = B * 13 - base;
        for (int idx = tid; idx < tot; idx += NTHREADS) {
            float v = 0.0f;
            if (idx < avail) v = inp[base + idx];
            sinp[idx] = v;
        }
    }
    __syncthreads();

    float mse = 0.0f, cons = 0.0f;

    if (row < B) {
        const float4* p4 = reinterpret_cast<const float4*>(pred + (size_t)row * 240);
        const float4* t4 = reinterpret_cast<const float4*>(targ + (size_t)row * 240);

        // ---- deep load burst: all 30 float4 loads issued before any use ----
        float4 p[15], t[15];
        #pragma unroll
        for (int i = 0; i < 10; ++i) p[i] = p4[sub + 4 * i];        // states
        #pragma unroll
        for (int i = 0; i < 5; ++i)  p[10 + i] = p4[40 + sub + 4 * i]; // controls
        #pragma unroll
        for (int i = 0; i < 10; ++i) t[i] = t4[sub + 4 * i];
        #pragma unroll
        for (int i = 0; i < 5; ++i)  t[10 + i] = t4[40 + sub + 4 * i];

        const float* in = &sinp[rloc * 13];
        const float ox0 = in[4],  oy0 = in[5];
        const float ox1 = in[7],  oy1 = in[8];
        const float ox2 = in[10], oy2 = in[11];

        float cv = 0.0f, sv = 0.0f, sum_dist = 0.0f;
        float sum_a = 0.0f, sum_w = 0.0f;
        float xlx = 0.0f, xly = 0.0f, xlth = 0.0f, xlv = 0.0f;  // x[39] (sub 3)

        // States x[k], k = sub + 4*i (float4 = px,py,th,v)
        #pragma unroll
        for (int i = 0; i < 10; ++i) {
            const int k = sub + 4 * i;
            const float4 pv = p[i];
            const float4 tv = t[i];
            float d0 = pv.x - tv.x, d1 = pv.y - tv.y;
            float d2 = pv.z - tv.z, d3 = pv.w - tv.w;
            mse += d0 * d0 + d1 * d1 + d2 * d2 + d3 * d3;

            if (k != 39) {               // states 0..38 feed telescoped sums
                float s, c;
                __sincosf(pv.z, &s, &c);
                cv += pv.w * c;
                sv += pv.w * s;
            } else {
                xlx = pv.x; xly = pv.y; xlth = pv.z; xlv = pv.w;
            }

            float dx, dy;
            dx = pv.x - ox0; dy = pv.y - oy0; sum_dist += sqrtf(dx * dx + dy * dy);
            dx = pv.x - ox1; dy = pv.y - oy1; sum_dist += sqrtf(dx * dx + dy * dy);
            dx = pv.x - ox2; dy = pv.y - oy2; sum_dist += sqrtf(dx * dx + dy * dy);
        }

        // Controls: float4 = (a,w,a,w)
        #pragma unroll
        for (int i = 0; i < 5; ++i) {
            const float4 pv = p[10 + i];
            const float4 tv = t[10 + i];
            float d0 = pv.x - tv.x, d1 = pv.y - tv.y;
            float d2 = pv.z - tv.z, d3 = pv.w - tv.w;
            mse += d0 * d0 + d1 * d1 + d2 * d2 + d3 * d3;
            sum_a += pv.x + pv.z;
            sum_w += pv.y + pv.w;
        }

        // Combine partials across the 4 lanes of this row's group.
        #pragma unroll
        for (int m = 1; m < 4; m <<= 1) {
            cv       += __shfl_xor(cv, m);
            sv       += __shfl_xor(sv, m);
            sum_a    += __shfl_xor(sum_a, m);
            sum_w    += __shfl_xor(sum_w, m);
            sum_dist += __shfl_xor(sum_dist, m);
        }

        // Bring x[39] (held by sub 3) to the whole 4-lane group.
        const int lane = tid & 63;
        const int src  = lane | 3;
        xlx  = __shfl(xlx,  src);
        xly  = __shfl(xly,  src);
        xlth = __shfl(xlth, src);
        xlv  = __shfl(xlv,  src);

        if (sub == 0) {
            const float x0px = in[0], x0py = in[1], x0th = in[2], x0v = in[3];
            const float r0 = in[6]  + 2.0f;
            const float r1 = in[9]  + 2.0f;
            const float r2 = in[12] + 2.0f;
            float s, c;
            __sincosf(x0th, &s, &c);
            cv += x0v * c;       // prev for k=0 is x0
            sv += x0v * s;

            float rr0 = xlx  - x0px - DT * cv;
            float rr1 = xly  - x0py - DT * sv;
            float rr2 = xlth - x0th - DT * sum_w;
            float rr3 = xlv  - x0v  - DT * sum_a;
            float dyn_err = sqrtf(rr0 * rr0 + rr1 * rr1 + rr2 * rr2 + rr3 * rr3);
            float rad2sum = r0 * r0 + r1 * r1 + r2 * r2;
            cons = dyn_err + sum_dist - 40.0f * rad2sum;
        }
    }

    // Wave-level reduction (64 lanes), then cross-wave via LDS.
    #pragma unroll
    for (int off = 32; off > 0; off >>= 1) {
        mse  += __shfl_down(mse,  off);
        cons += __shfl_down(cons, off);
    }

    __shared__ float smse[NTHREADS / 64];
    __shared__ float scons[NTHREADS / 64];
    const int wid  = threadIdx.x >> 6;
    const int lane = threadIdx.x & 63;
    if (lane == 0) { smse[wid] = mse; scons[wid] = cons; }
    __syncthreads();
    if (threadIdx.x == 0) {
        float m = smse[0] + smse[1] + smse[2] + smse[3];
        float c = scons[0] + scons[1] + scons[2] + scons[3];
        partial[2 * blockIdx.x]     = m;
        partial[2 * blockIdx.x + 1] = c;
    }
}

__global__ __launch_bounds__(256) void finalize_kernel(
    const float* __restrict__ partial, float* __restrict__ out,
    int nblocks, int B)
{
    float m = 0.0f, c = 0.0f;
    for (int i = threadIdx.x; i < nblocks; i += 256) {
        m += partial[2 * i];
        c += partial[2 * i + 1];
    }
    #pragma unroll
    for (int off = 32; off > 0; off >>= 1) {
        m += __shfl_down(m, off);
        c += __shfl_down(c, off);
    }
    __shared__ float sm[4], sc[4];
    const int wid  = threadIdx.x >> 6;
    const int lane = threadIdx.x & 63;
    if (lane == 0) { sm[wid] = m; sc[wid] = c; }
    __syncthreads();
    if (threadIdx.x == 0) {
        float mm = sm[0] + sm[1] + sm[2] + sm[3];
        float cc = sc[0] + sc[1] + sc[2] + sc[3];
        float nb = (float)B;
        out[0] = mm / (nb * 240.0f) + cc / nb;
    }
}

extern "C" void kernel_launch(void* const* d_in, const int* in_sizes, int n_in,
                              void* d_out, int out_size, void* d_ws, size_t ws_size,
                              hipStream_t stream) {
    const float* pred = (const float*)d_in[0];
    const float* targ = (const float*)d_in[1];
    const float* inp  = (const float*)d_in[2];
    float* out = (float*)d_out;
    float* ws  = (float*)d_ws;

    const int B = in_sizes[0] / 240;
    const int grid = (B + ROWS_PER_BLOCK - 1) / ROWS_PER_BLOCK;

    constraint_main_kernel<<<grid, NTHREADS, 0, stream>>>(pred, targ, inp, ws, B);
    finalize_kernel<<<1, 256, 0, stream>>>(ws, out, grid, B);
}